// Round 1
// baseline (586.287 us; speedup 1.0000x reference)
//
#include <hip/hip_runtime.h>

// ---------------------------------------------------------------------------
// GCN block: 3 x (GCNConv -> ReLU -> global_mean_pool)
// 10 dispatches (gaps cost ~9us each; cooperative grid.sync measured ~100us
// per sync on 8-XCD MI355X (R9) — plain dispatches win):
//   k_prep:      zero padded count-lines + bsum + graph bounds + WbT transpose
//   k_phase1:    heterogeneous: blocks[0..782) = layer-1 MFMA GEMM reading
//                fp32 x with in-register bf16 cast; blocks[782..) = NON-
//                RETURNING packed 64-bit atomics: one atomicAdd(u64) per edge
//                builds cnt (bits 40+) AND fixed-point weighted degree
//                (bits 0..39, w*2^22) on a 64B-padded per-node line.
//                (R10: returning per-edge atomics + compact cnt was latency-
//                bound at 90us, VALUBusy 3.6%.)
//   k_scan1:     per-block exclusive scan (pre) + raw block sums (bsum) +
//                dinv = rsqrt(1+deg) + seed padded cursor with local prefix
//   k_scatter:   inline LDS scan of 128 block sums; rank claimed HERE via
//                returning atomicAdd on the padded cursor (latency hidden by
//                csr store + dinv gathers); writes NORMALIZED csr.y =
//                dinv[r]*w*dinv[c] directly; ptrv
//   per layer:   k_agg (paired-edge gather, R8-proven loop) ->
//                k_gemm_pool (next-layer GEMM + previous-layer pool fused;
//                final call is pool-only with nbGemm=0)
// k_degdinv / k_norm are gone (folded into scan1/scatter).
// ---------------------------------------------------------------------------

typedef short short8 __attribute__((ext_vector_type(8)));   // 8 bf16 (4 VGPR)
typedef float f32x4  __attribute__((ext_vector_type(4)));   // MFMA C/D

__device__ inline unsigned pack_bf16x2(float a, float b) {
    unsigned ua = __float_as_uint(a);
    ua = (ua + 0x7FFFu + ((ua >> 16) & 1u)) >> 16;       // RNE
    unsigned ub = __float_as_uint(b);
    ub = (ub + 0x7FFFu + ((ub >> 16) & 1u)) >> 16;
    return ua | (ub << 16);
}
__device__ inline ushort bf16_1(float a) {
    unsigned ua = __float_as_uint(a);
    return (ushort)((ua + 0x7FFFu + ((ua >> 16) & 1u)) >> 16);
}
__device__ inline float bf_lo(unsigned u) { return __uint_as_float(u << 16); }
__device__ inline float bf_hi(unsigned u) { return __uint_as_float(u & 0xFFFF0000u); }

// ---- shared device bodies -------------------------------------------------

// One block = 128 rows x 128 cols of hl = H @ W (v_mfma_f32_16x16x32_bf16).
// Wave = 32 rows: 2 m-strips x 8 n-tiles, 64 MFMAs. A-frag 16B/lane
// contiguous (F32IN: 32B fp32 -> in-register bf16 cast). B from WbT[n][k].
// Epilogue via LDS (sOut, 8192 u32) -> coalesced u32 stores.
template <bool F32IN>
__device__ __forceinline__ void gemm_tile(const void* __restrict__ Hin,
                                          const ushort* __restrict__ WbT,
                                          unsigned* __restrict__ O, int M,
                                          int bid, unsigned* sOut) {
    int lane = threadIdx.x & 63;
    int wv = threadIdx.x >> 6;
    int quad = lane >> 4;
    int mrow = lane & 15;
    int m0 = bid * 128 + wv * 32;
    int r0 = m0 + mrow;
    int r1 = r0 + 16;
    int r0c = r0 < M ? r0 : M - 1;             // clamp loads, guard stores
    int r1c = r1 < M ? r1 : M - 1;

    short8 a0[4], a1[4];
    if (F32IN) {
        const float* Hf = (const float*)Hin;
#pragma unroll
        for (int s = 0; s < 4; s++) {          // k-step s covers k in [32s,32s+32)
            const float4* p0 = (const float4*)(Hf + (size_t)r0c * 128 + s * 32 + quad * 8);
            const float4* p1 = (const float4*)(Hf + (size_t)r1c * 128 + s * 32 + quad * 8);
            float4 f0 = p0[0], f1 = p0[1];
            float4 g0 = p1[0], g1 = p1[1];
            union { short8 s8; unsigned u[4]; } t0, t1;
            t0.u[0] = pack_bf16x2(f0.x, f0.y); t0.u[1] = pack_bf16x2(f0.z, f0.w);
            t0.u[2] = pack_bf16x2(f1.x, f1.y); t0.u[3] = pack_bf16x2(f1.z, f1.w);
            t1.u[0] = pack_bf16x2(g0.x, g0.y); t1.u[1] = pack_bf16x2(g0.z, g0.w);
            t1.u[2] = pack_bf16x2(g1.x, g1.y); t1.u[3] = pack_bf16x2(g1.z, g1.w);
            a0[s] = t0.s8; a1[s] = t1.s8;
        }
    } else {
        const unsigned* Hb = (const unsigned*)Hin;
#pragma unroll
        for (int s = 0; s < 4; s++) {
            a0[s] = *(const short8*)(Hb + (size_t)r0c * 64 + s * 16 + quad * 4);
            a1[s] = *(const short8*)(Hb + (size_t)r1c * 64 + s * 16 + quad * 4);
        }
    }
    f32x4 acc0[8], acc1[8];
#pragma unroll
    for (int t = 0; t < 8; t++) {
        acc0[t] = (f32x4){0.f, 0.f, 0.f, 0.f};
        acc1[t] = (f32x4){0.f, 0.f, 0.f, 0.f};
    }
#pragma unroll
    for (int s = 0; s < 4; s++) {
#pragma unroll
        for (int t = 0; t < 8; t++) {
            short8 b = *(const short8*)(WbT + (t * 16 + mrow) * 128 + s * 32 + quad * 8);
            acc0[t] = __builtin_amdgcn_mfma_f32_16x16x32_bf16(a0[s], b, acc0[t], 0, 0, 0);
            acc1[t] = __builtin_amdgcn_mfma_f32_16x16x32_bf16(a1[s], b, acc1[t], 0, 0, 0);
        }
    }
    // C/D layout: col = lane&15, row = quad*4 + reg.
    ushort* so = (ushort*)(sOut + wv * 32 * 64);
#pragma unroll
    for (int t = 0; t < 8; t++) {
#pragma unroll
        for (int r = 0; r < 4; r++) {
            int lr = quad * 4 + r;
            int c = t * 16 + mrow;
            so[lr * 128 + c] = bf16_1(acc0[t][r]);
            so[(lr + 16) * 128 + c] = bf16_1(acc1[t][r]);
        }
    }
    __syncthreads();
    const unsigned* si = sOut + wv * 32 * 64;
#pragma unroll 8
    for (int r = 0; r < 32; r++) {
        int row = m0 + r;
        if (row < M) O[(size_t)row * 64 + lane] = si[r * 64 + lane];
    }
}

// One block per graph: stream the sorted node segment, 4 waves stride it,
// LDS-combine (part = 512 floats), divide by count, write. No atomics.
__device__ __forceinline__ void pool_tile(const unsigned* __restrict__ HB,
                                          const int* __restrict__ gb,
                                          float* __restrict__ outp, int g,
                                          float* part) {
    int lane = threadIdx.x & 63, w = threadIdx.x >> 6;
    int s = gb[g], e = gb[g + 1];
    float ax = 0.f, ay = 0.f;
    for (int i = s + w; i < e; i += 4) {
        unsigned u = HB[(size_t)i * 64 + lane];
        ax += bf_lo(u); ay += bf_hi(u);
    }
    part[w * 128 + lane * 2] = ax;
    part[w * 128 + lane * 2 + 1] = ay;
    __syncthreads();
    if (threadIdx.x < 128) {
        float sum = part[threadIdx.x] + part[128 + threadIdx.x]
                  + part[256 + threadIdx.x] + part[384 + threadIdx.x];
        float c = (float)(e - s);
        outp[g * 128 + threadIdx.x] = sum / fmaxf(c, 1.0f);
    }
}

// ---- kernels --------------------------------------------------------------

// Fused pre-pass: zero padded count-lines + bsum, graph bounds, W transpose+cast.
__global__ void k_prep(unsigned long long* __restrict__ lines, int N,
                       int* __restrict__ bsum,
                       const int* __restrict__ batch, int* __restrict__ gb, int G,
                       const float* __restrict__ W0, const float* __restrict__ W1,
                       const float* __restrict__ W2, ushort* __restrict__ WbT) {
    int id = blockIdx.x * blockDim.x + threadIdx.x;
    if (id < N) lines[(size_t)id * 8] = 0ULL;   // one 64B line per node, slot 0
    if (id < 128) bsum[id] = 0;
    if (id <= G) {
        int lo = 0, hi = N;
        while (lo < hi) { int mid = (lo + hi) >> 1; if (batch[mid] < id) lo = mid + 1; else hi = mid; }
        gb[id] = lo;
    }
    if (id < 3 * 16384) {
        int l = id >> 14;
        const float* W = (l == 0) ? W0 : ((l == 1) ? W1 : W2);
        int id2 = id & 16383;
        int n = id2 & 127, k = id2 >> 7;
        WbT[l * 16384 + n * 128 + k] = bf16_1(W[k * 128 + n]);
    }
}

// Heterogeneous: blocks[0..nbGemm) = layer-1 GEMM (fp32 x, in-reg bf16 cast);
// blocks[nbGemm..) = non-returning packed count+degree atomics, 4 edges/thread.
// Packed u64 per node line: bits[63:40] = in-degree count, bits[39:0] =
// sum(w * 2^22) fixed-point (w in [0,1), max bucket ~40 edges -> no overflow,
// quantization error <= ~2e-6, far below bf16 noise).
__global__ __launch_bounds__(256) void k_phase1(const int* __restrict__ ei,
                                                const float* __restrict__ ew,
                                                unsigned long long* __restrict__ lines,
                                                int E,
                                                const float* __restrict__ x,
                                                const ushort* __restrict__ WbT,
                                                unsigned* __restrict__ O, int M,
                                                int nbGemm) {
    __shared__ unsigned sBuf[8192];            // 32 KB (gemm epilogue)
    if (blockIdx.x < nbGemm) {
        gemm_tile<true>(x, WbT, O, M, blockIdx.x, sBuf);
        return;
    }
    int base = (blockIdx.x - nbGemm) * 1024 + threadIdx.x;
#pragma unroll
    for (int q = 0; q < 4; q++) {
        int e = base + q * 256;
        if (e < E) {
            int c = ei[E + e];
            float w = ew[e];
            unsigned long long pkt =
                (1ULL << 40) | (unsigned long long)(unsigned)(w * 4194304.0f + 0.5f);
            atomicAdd(&lines[(size_t)c * 8], pkt);   // fire-and-forget
        }
    }
}

// Per-block exclusive scan of padded counts -> pre, raw block totals -> bsum,
// dinv = rsqrt(1 + deg) (self-loop weight 1), cursor seed = local prefix.
__global__ __launch_bounds__(1024) void k_scan1(unsigned long long* __restrict__ lines,
                                                int* __restrict__ pre,
                                                int* __restrict__ bsum,
                                                float* __restrict__ dinv, int n) {
    __shared__ int wsum[16];
    int t = threadIdx.x, lane = t & 63, w = t >> 6;
    int i = blockIdx.x * 1024 + t;
    int v = 0; float dg = 1.0f;
    if (i < n) {
        unsigned long long u = lines[(size_t)i * 8];
        v = (int)(u >> 40);
        dg = 1.0f + (float)(u & 0xFFFFFFFFFFULL) * (1.0f / 4194304.0f);
    }
    int x = v;
#pragma unroll
    for (int off = 1; off < 64; off <<= 1) {
        int y = __shfl_up(x, off, 64);
        if (lane >= off) x += y;
    }
    if (lane == 63) wsum[w] = x;
    __syncthreads();
    int woff = 0, tot = 0;
#pragma unroll
    for (int q = 0; q < 16; q++) { int s = wsum[q]; if (q < w) woff += s; tot += s; }
    if (i < n) {
        int ex = woff + x - v;
        pre[i] = ex;
        ((int*)lines)[(size_t)i * 16] = ex;    // padded cursor seed (low word)
        dinv[i] = rsqrtf(dg);
    }
    if (t == 0) bsum[blockIdx.x] = tot;
}

// Scatter edges to CSR slots. Each block scans the 128 raw block sums in LDS
// (scan2 folded in); in-bucket rank claimed via returning atomicAdd on the
// 64B-padded cursor (latency hidden by the surrounding real work); csr.y is
// written ALREADY NORMALIZED = dinv[r]*w*dinv[c]; also materializes ptrv.
__global__ __launch_bounds__(256) void k_scatter(const int* __restrict__ ei,
                                                 const float* __restrict__ ew,
                                                 const int* __restrict__ pre,
                                                 const int* __restrict__ bsumRaw,
                                                 int* __restrict__ ptrv,
                                                 const float* __restrict__ dinv,
                                                 int* __restrict__ cur,
                                                 int2* __restrict__ csr, int E, int N) {
    __shared__ int sRaw[256];
    __shared__ int sPre[256];
    __shared__ int sWt[4];
    int t = threadIdx.x;
    sRaw[t] = (t < 128) ? bsumRaw[t] : 0;
    __syncthreads();
    int lane = t & 63, w2 = t >> 6;
    int v = sRaw[t];
    int x = v;
#pragma unroll
    for (int off = 1; off < 64; off <<= 1) {
        int y = __shfl_up(x, off, 64);
        if (lane >= off) x += y;
    }
    if (lane == 63) sWt[w2] = x;
    __syncthreads();
    int base = 0;
#pragma unroll
    for (int q = 0; q < 4; q++) { if (q < w2) base += sWt[q]; }
    sPre[t] = base + x - v;                    // exclusive prefix of block sums
    __syncthreads();
    int e = blockIdx.x * 256 + t;
    if (e < N) ptrv[e] = pre[e] + sPre[e >> 10];
    if (e == 0) ptrv[N] = sWt[0] + sWt[1];     // grand total (sums in waves 0/1)
    if (e >= E) return;
    int r = ei[e];
    int c = ei[E + e];
    float y = dinv[r] * ew[e] * dinv[c];       // normalize here (k_norm folded)
    int slot = sPre[c >> 10] + atomicAdd(&cur[(size_t)c * 16], 1);
    int2 mv; mv.x = r; mv.y = __float_as_int(y);
    csr[slot] = mv;
}

// One wave per node, paired-edge (R8-proven loop: 4 pairs = 8 edges/iter).
__global__ __launch_bounds__(256) void k_agg(const unsigned* __restrict__ HL,
                                             const int* __restrict__ ptr,
                                             const int2* __restrict__ csr,
                                             const float* __restrict__ dinv,
                                             const float* __restrict__ bias,
                                             unsigned* __restrict__ Hout, int M) {
    __shared__ int2 sM[4 * 64];
    int node = (int)((blockIdx.x * blockDim.x + threadIdx.x) >> 6);
    if (node >= M) return;
    int lane = threadIdx.x & 63;
    int half = lane >> 5;                 // 0: even edges, 1: odd edges
    int q = lane & 31;                    // features 4q .. 4q+3
    int2* mbase = &sM[(threadIdx.x >> 6) * 64];
    int e0 = ptr[node], e1 = ptr[node + 1];
    int deg = e1 - e0;
    int nbv = deg < 64 ? deg : 64;
    if (lane < nbv) mbase[lane] = csr[e0 + lane];   // one coalesced load
    const uint2* HL2 = (const uint2*)HL;            // row = 32 uint2
    float di = dinv[node];
    float sn = (half == 0) ? di * di : 0.f;         // self-loop on half 0 only
    uint2 us = HL2[(size_t)node * 32 + q];
    float a0 = sn * bf_lo(us.x), a1 = sn * bf_hi(us.x);
    float a2 = sn * bf_lo(us.y), a3 = sn * bf_hi(us.y);
    int j = half;
    for (; j + 8 <= nbv; j += 8) {                  // 4 pairs in flight
        int2 m[4]; uint2 u[4];
#pragma unroll
        for (int t = 0; t < 4; t++) m[t] = mbase[j + 2 * t];
#pragma unroll
        for (int t = 0; t < 4; t++) u[t] = HL2[(size_t)m[t].x * 32 + q];
#pragma unroll
        for (int t = 0; t < 4; t++) {
            float nv = __int_as_float(m[t].y);
            a0 += nv * bf_lo(u[t].x); a1 += nv * bf_hi(u[t].x);
            a2 += nv * bf_lo(u[t].y); a3 += nv * bf_hi(u[t].y);
        }
    }
    for (; j < nbv; j += 2) {
        int2 m = mbase[j];
        uint2 u = HL2[(size_t)m.x * 32 + q];
        float nv = __int_as_float(m.y);
        a0 += nv * bf_lo(u.x); a1 += nv * bf_hi(u.x);
        a2 += nv * bf_lo(u.y); a3 += nv * bf_hi(u.y);
    }
    for (int e = e0 + 64 + half; e < e1; e += 2) {  // rare high-degree tail
        int2 m = csr[e];
        uint2 u = HL2[(size_t)m.x * 32 + q];
        float nv = __int_as_float(m.y);
        a0 += nv * bf_lo(u.x); a1 += nv * bf_hi(u.x);
        a2 += nv * bf_lo(u.y); a3 += nv * bf_hi(u.y);
    }
    a0 += __shfl_xor(a0, 32, 64);
    a1 += __shfl_xor(a1, 32, 64);
    a2 += __shfl_xor(a2, 32, 64);
    a3 += __shfl_xor(a3, 32, 64);
    float4 bv = ((const float4*)bias)[q];
    float r0 = fmaxf(a0 + bv.x, 0.f);
    float r1 = fmaxf(a1 + bv.y, 0.f);
    float r2 = fmaxf(a2 + bv.z, 0.f);
    float r3 = fmaxf(a3 + bv.w, 0.f);
    if (half == 0) {
        uint2 pv;
        pv.x = pack_bf16x2(r0, r1);
        pv.y = pack_bf16x2(r2, r3);
        ((uint2*)(Hout + (size_t)node * 64))[q] = pv;
    }
}

// Heterogeneous: blocks[0..nbGemm) = next-layer GEMM reading Hb;
// blocks[nbGemm..nbGemm+G) = pool of the SAME Hb into outp (both depend only
// on the preceding agg). nbGemm=0 -> pool-only (final layer).
__global__ __launch_bounds__(256) void k_gemm_pool(const unsigned* __restrict__ Hb,
                                                   const ushort* __restrict__ WbT,
                                                   unsigned* __restrict__ O, int M,
                                                   const int* __restrict__ gb,
                                                   float* __restrict__ outp,
                                                   int nbGemm) {
    __shared__ unsigned sBuf[8192];            // gemm epilogue / pool partials
    if (blockIdx.x < nbGemm) {
        gemm_tile<false>(Hb, WbT, O, M, blockIdx.x, sBuf);
        return;
    }
    pool_tile(Hb, gb, outp, blockIdx.x - nbGemm, (float*)sBuf);
}

extern "C" void kernel_launch(void* const* d_in, const int* in_sizes, int n_in,
                              void* d_out, int out_size, void* d_ws, size_t ws_size,
                              hipStream_t stream) {
    const float* x     = (const float*)d_in[0];
    const int*   ei    = (const int*)d_in[1];
    const float* ew    = (const float*)d_in[2];
    const int*   batch = (const int*)d_in[3];
    const float* Wt[3] = {(const float*)d_in[4], (const float*)d_in[6], (const float*)d_in[8]};
    const float* bt[3] = {(const float*)d_in[5], (const float*)d_in[7], (const float*)d_in[9]};
    float* out = (float*)d_out;

    const int D = 128;
    const int N = in_sizes[0] / D;       // 100000
    const int E = in_sizes[2];           // 1600000
    const int G = out_size / (3 * D);    // 256

    // workspace carve-up (256 B aligned)
    char* p = (char*)d_ws;
    auto alloc = [&](size_t bytes) {
        void* r = (void*)p;
        p += (bytes + 255) & ~(size_t)255;
        return r;
    };
    int*      ptr    = (int*)alloc((size_t)(N + 1) * 4);
    int*      pre    = (int*)alloc((size_t)N * 4);
    int*      bsum   = (int*)alloc((size_t)128 * 4);
    int*      gb     = (int*)alloc((size_t)(G + 1) * 4);
    float*    dinv   = (float*)alloc((size_t)N * 4);
    ushort*   WbT    = (ushort*)alloc((size_t)3 * 16384 * 2);
    int2*     csr    = (int2*)alloc((size_t)E * 8);
    unsigned* bufHL  = (unsigned*)alloc((size_t)N * 64 * 4);  // hl, bf16-packed
    unsigned* bufH   = (unsigned*)alloc((size_t)N * 64 * 4);  // h,  bf16-packed
    // padded count/deg/cursor lines (64B per node, 6.4MB): alias bufH —
    // lines are dead before k_agg's first write of bufH.
    unsigned long long* lines = (unsigned long long*)bufH;

    int nb = (N + 1023) / 1024;                 // 98 scan blocks (<=128)
    int nbGemm = (N + 127) / 128;               // 782 gemm blocks
    int nbAtomic = (E + 1023) / 1024;           // 1563 atomic blocks (4 e/thr)
    int prepWork = N > 3 * 16384 ? N : 3 * 16384;

    k_prep<<<(prepWork + 255) / 256, 256, 0, stream>>>(lines, N, bsum, batch, gb, G,
                                                       Wt[0], Wt[1], Wt[2], WbT);
    // layer-1 GEMM fused with the (non-returning) count/degree pass
    k_phase1<<<nbGemm + nbAtomic, 256, 0, stream>>>(ei, ew, lines, E,
                                                    x, WbT, bufHL, N, nbGemm);
    k_scan1<<<nb, 1024, 0, stream>>>(lines, pre, bsum, dinv, N);
    k_scatter<<<(E + 255) / 256, 256, 0, stream>>>(ei, ew, pre, bsum, ptr, dinv,
                                                   (int*)lines, csr, E, N);

    // L1 aggregate, then fused (gemm_{l+1} + pool_l), final pool-only.
    k_agg<<<(N + 3) / 4, 256, 0, stream>>>(bufHL, ptr, csr, dinv, bt[0], bufH, N);
    k_gemm_pool<<<nbGemm + G, 256, 0, stream>>>(bufH, WbT + 16384, bufHL, N,
                                                gb, out + 0 * (size_t)G * D, nbGemm);
    k_agg<<<(N + 3) / 4, 256, 0, stream>>>(bufHL, ptr, csr, dinv, bt[1], bufH, N);
    k_gemm_pool<<<nbGemm + G, 256, 0, stream>>>(bufH, WbT + 2 * 16384, bufHL, N,
                                                gb, out + 1 * (size_t)G * D, nbGemm);
    k_agg<<<(N + 3) / 4, 256, 0, stream>>>(bufHL, ptr, csr, dinv, bt[2], bufH, N);
    k_gemm_pool<<<G, 256, 0, stream>>>(bufH, WbT, nullptr, 0,
                                       gb, out + 2 * (size_t)G * D, 0);
}

// Round 2
// 524.464 us; speedup vs baseline: 1.1179x; 1.1179x over previous
//
#include <hip/hip_runtime.h>

// ---------------------------------------------------------------------------
// GCN block: 3 x (GCNConv -> ReLU -> global_mean_pool)
// 12 dispatches. ZERO device-scope atomics anywhere (R11 finding: 1.6M
// device atomics are rate-limited ~18G/s at the memory-side coherence point
// regardless of structure — returning/non-returning/padded all ~90us, with
// ~45MB of per-op writeback visible in WRITE_SIZE). CSR build is now a
// 2-level multisplit using only LDS atomics:
//   k_prep:      graph bounds + WbT transpose/cast
//   k_phase1:    heterogeneous: blocks[0..782) = layer-1 MFMA GEMM (fp32 x,
//                in-reg bf16 cast); blocks[782..782+196) = pass A: per-block
//                LDS histogram over 782 coarse buckets (col>>7), plain
//                writes hist[bucket][blk] — no atomics.
//   k_scan1:     proven 1024-chunk exclusive scan over the 153K hist matrix
//                (bucket-major) -> pre + 150 block sums
//   k_scat:      inline LDS scan of block sums (proven pattern); per-block
//                LDS-atomic ranks; write packed (r|c_local<<17, w) records
//                into bucket-contiguous regions (recs aliases dead bufH);
//                block 0 emits bucketStart[]
//   k_fin:       one block per bucket: per-node count + weighted degree in
//                LDS (128 counters), dinv=rsqrt(1+wdeg), ptr, then in-bucket
//                scatter to final CSR with csr.y = w*dinv[c]
//   k_norm2:     csr.y *= dinv[r] (coalesced RMW, dinv gathers L2-resident)
//   per layer:   k_agg (paired-edge gather, R8-proven loop) ->
//                k_gemm_pool (next-layer GEMM + previous-layer pool fused;
//                final call is pool-only with nbGemm=0)
// hist/pre alias the csr buffer (dead before k_fin writes csr).
// ---------------------------------------------------------------------------

typedef short short8 __attribute__((ext_vector_type(8)));   // 8 bf16 (4 VGPR)
typedef float f32x4  __attribute__((ext_vector_type(4)));   // MFMA C/D

__device__ inline unsigned pack_bf16x2(float a, float b) {
    unsigned ua = __float_as_uint(a);
    ua = (ua + 0x7FFFu + ((ua >> 16) & 1u)) >> 16;       // RNE
    unsigned ub = __float_as_uint(b);
    ub = (ub + 0x7FFFu + ((ub >> 16) & 1u)) >> 16;
    return ua | (ub << 16);
}
__device__ inline ushort bf16_1(float a) {
    unsigned ua = __float_as_uint(a);
    return (ushort)((ua + 0x7FFFu + ((ua >> 16) & 1u)) >> 16);
}
__device__ inline float bf_lo(unsigned u) { return __uint_as_float(u << 16); }
__device__ inline float bf_hi(unsigned u) { return __uint_as_float(u & 0xFFFF0000u); }

// ---- shared device bodies -------------------------------------------------

// One block = 128 rows x 128 cols of hl = H @ W (v_mfma_f32_16x16x32_bf16).
// Wave = 32 rows: 2 m-strips x 8 n-tiles, 64 MFMAs. A-frag 16B/lane
// contiguous (F32IN: 32B fp32 -> in-register bf16 cast). B from WbT[n][k].
// Epilogue via LDS (sOut, 8192 u32) -> coalesced u32 stores.
template <bool F32IN>
__device__ __forceinline__ void gemm_tile(const void* __restrict__ Hin,
                                          const ushort* __restrict__ WbT,
                                          unsigned* __restrict__ O, int M,
                                          int bid, unsigned* sOut) {
    int lane = threadIdx.x & 63;
    int wv = threadIdx.x >> 6;
    int quad = lane >> 4;
    int mrow = lane & 15;
    int m0 = bid * 128 + wv * 32;
    int r0 = m0 + mrow;
    int r1 = r0 + 16;
    int r0c = r0 < M ? r0 : M - 1;             // clamp loads, guard stores
    int r1c = r1 < M ? r1 : M - 1;

    short8 a0[4], a1[4];
    if (F32IN) {
        const float* Hf = (const float*)Hin;
#pragma unroll
        for (int s = 0; s < 4; s++) {          // k-step s covers k in [32s,32s+32)
            const float4* p0 = (const float4*)(Hf + (size_t)r0c * 128 + s * 32 + quad * 8);
            const float4* p1 = (const float4*)(Hf + (size_t)r1c * 128 + s * 32 + quad * 8);
            float4 f0 = p0[0], f1 = p0[1];
            float4 g0 = p1[0], g1 = p1[1];
            union { short8 s8; unsigned u[4]; } t0, t1;
            t0.u[0] = pack_bf16x2(f0.x, f0.y); t0.u[1] = pack_bf16x2(f0.z, f0.w);
            t0.u[2] = pack_bf16x2(f1.x, f1.y); t0.u[3] = pack_bf16x2(f1.z, f1.w);
            t1.u[0] = pack_bf16x2(g0.x, g0.y); t1.u[1] = pack_bf16x2(g0.z, g0.w);
            t1.u[2] = pack_bf16x2(g1.x, g1.y); t1.u[3] = pack_bf16x2(g1.z, g1.w);
            a0[s] = t0.s8; a1[s] = t1.s8;
        }
    } else {
        const unsigned* Hb = (const unsigned*)Hin;
#pragma unroll
        for (int s = 0; s < 4; s++) {
            a0[s] = *(const short8*)(Hb + (size_t)r0c * 64 + s * 16 + quad * 4);
            a1[s] = *(const short8*)(Hb + (size_t)r1c * 64 + s * 16 + quad * 4);
        }
    }
    f32x4 acc0[8], acc1[8];
#pragma unroll
    for (int t = 0; t < 8; t++) {
        acc0[t] = (f32x4){0.f, 0.f, 0.f, 0.f};
        acc1[t] = (f32x4){0.f, 0.f, 0.f, 0.f};
    }
#pragma unroll
    for (int s = 0; s < 4; s++) {
#pragma unroll
        for (int t = 0; t < 8; t++) {
            short8 b = *(const short8*)(WbT + (t * 16 + mrow) * 128 + s * 32 + quad * 8);
            acc0[t] = __builtin_amdgcn_mfma_f32_16x16x32_bf16(a0[s], b, acc0[t], 0, 0, 0);
            acc1[t] = __builtin_amdgcn_mfma_f32_16x16x32_bf16(a1[s], b, acc1[t], 0, 0, 0);
        }
    }
    // C/D layout: col = lane&15, row = quad*4 + reg.
    ushort* so = (ushort*)(sOut + wv * 32 * 64);
#pragma unroll
    for (int t = 0; t < 8; t++) {
#pragma unroll
        for (int r = 0; r < 4; r++) {
            int lr = quad * 4 + r;
            int c = t * 16 + mrow;
            so[lr * 128 + c] = bf16_1(acc0[t][r]);
            so[(lr + 16) * 128 + c] = bf16_1(acc1[t][r]);
        }
    }
    __syncthreads();
    const unsigned* si = sOut + wv * 32 * 64;
#pragma unroll 8
    for (int r = 0; r < 32; r++) {
        int row = m0 + r;
        if (row < M) O[(size_t)row * 64 + lane] = si[r * 64 + lane];
    }
}

// One block per graph: stream the sorted node segment, 4 waves stride it,
// LDS-combine (part = 512 floats), divide by count, write. No atomics.
__device__ __forceinline__ void pool_tile(const unsigned* __restrict__ HB,
                                          const int* __restrict__ gb,
                                          float* __restrict__ outp, int g,
                                          float* part) {
    int lane = threadIdx.x & 63, w = threadIdx.x >> 6;
    int s = gb[g], e = gb[g + 1];
    float ax = 0.f, ay = 0.f;
    for (int i = s + w; i < e; i += 4) {
        unsigned u = HB[(size_t)i * 64 + lane];
        ax += bf_lo(u); ay += bf_hi(u);
    }
    part[w * 128 + lane * 2] = ax;
    part[w * 128 + lane * 2 + 1] = ay;
    __syncthreads();
    if (threadIdx.x < 128) {
        float sum = part[threadIdx.x] + part[128 + threadIdx.x]
                  + part[256 + threadIdx.x] + part[384 + threadIdx.x];
        float c = (float)(e - s);
        outp[g * 128 + threadIdx.x] = sum / fmaxf(c, 1.0f);
    }
}

// ---- kernels --------------------------------------------------------------

// Pre-pass: graph bounds + W transpose+cast (no zeroing needed anymore).
__global__ void k_prep(const int* __restrict__ batch, int* __restrict__ gb,
                       int G, int N,
                       const float* __restrict__ W0, const float* __restrict__ W1,
                       const float* __restrict__ W2, ushort* __restrict__ WbT) {
    int id = blockIdx.x * blockDim.x + threadIdx.x;
    if (id <= G) {
        int lo = 0, hi = N;
        while (lo < hi) { int mid = (lo + hi) >> 1; if (batch[mid] < id) lo = mid + 1; else hi = mid; }
        gb[id] = lo;
    }
    if (id < 3 * 16384) {
        int l = id >> 14;
        const float* W = (l == 0) ? W0 : ((l == 1) ? W1 : W2);
        int id2 = id & 16383;
        int n = id2 & 127, k = id2 >> 7;
        WbT[l * 16384 + n * 128 + k] = bf16_1(W[k * 128 + n]);
    }
}

// Heterogeneous: blocks[0..nbGemm) = layer-1 GEMM (fp32 x, in-reg bf16 cast);
// blocks[nbGemm..nbGemm+nbCount) = pass A: LDS histogram over nbGemm (=nbkt)
// coarse buckets (col>>7), 8192 edges/block, plain hist writes. NO global
// atomics.
__global__ __launch_bounds__(256) void k_phase1(const int* __restrict__ ei,
                                                int* __restrict__ hist, int E,
                                                const float* __restrict__ x,
                                                const ushort* __restrict__ WbT,
                                                unsigned* __restrict__ O, int M,
                                                int nbGemm, int nbCount) {
    __shared__ unsigned sBuf[8192];            // 32 KB (gemm epilogue / hist)
    if (blockIdx.x < nbGemm) {
        gemm_tile<true>(x, WbT, O, M, blockIdx.x, sBuf);
        return;
    }
    int blk = blockIdx.x - nbGemm;
    unsigned* hcnt = sBuf;                     // nbkt (<=784) counters
    int t = threadIdx.x;
    for (int i = t; i < nbGemm; i += 256) hcnt[i] = 0;
    __syncthreads();
    int base = blk * 8192;
    for (int i = t; i < 8192; i += 256) {
        int e = base + i;
        if (e < E) atomicAdd(&hcnt[(unsigned)ei[E + e] >> 7], 1u);  // LDS atomic
    }
    __syncthreads();
    for (int b = t; b < nbGemm; b += 256)      // bucket-major layout
        hist[b * nbCount + blk] = (int)hcnt[b];
}

// Proven 1024-chunk exclusive scan: pre[i] = chunk-local exclusive prefix,
// bsum[chunk] = chunk total. n = nbkt*nbCount (~153K).
__global__ __launch_bounds__(1024) void k_scan1(const int* __restrict__ cnt,
                                                int* __restrict__ pre,
                                                int* __restrict__ bsum, int n) {
    __shared__ int wsum[16];
    int t = threadIdx.x, lane = t & 63, w = t >> 6;
    int i = blockIdx.x * 1024 + t;
    int v = (i < n) ? cnt[i] : 0;
    int x = v;
#pragma unroll
    for (int off = 1; off < 64; off <<= 1) {
        int y = __shfl_up(x, off, 64);
        if (lane >= off) x += y;
    }
    if (lane == 63) wsum[w] = x;
    __syncthreads();
    int woff = 0, tot = 0;
#pragma unroll
    for (int q = 0; q < 16; q++) { int s = wsum[q]; if (q < w) woff += s; tot += s; }
    if (i < n) pre[i] = woff + x - v;
    if (t == 0) bsum[blockIdx.x] = tot;
}

// Pass C: inline LDS scan of the (<=256) chunk sums; per-bucket bases into
// LDS; per-edge rank via LDS atomic; write packed records into bucket-
// contiguous regions. Block 0 also emits bucketStart[].
__global__ __launch_bounds__(256) void k_scat(const int* __restrict__ ei,
                                              const float* __restrict__ ew,
                                              const int* __restrict__ pre,
                                              const int* __restrict__ bsumRaw,
                                              int* __restrict__ bucketStart,
                                              int2* __restrict__ recs,
                                              int E, int nbkt, int nbCount,
                                              int nbScan) {
    __shared__ int sRaw[256];
    __shared__ int sPre[256];
    __shared__ int sWt[4];
    __shared__ int sBase[784];
    __shared__ unsigned rk[784];
    int t = threadIdx.x;
    sRaw[t] = (t < nbScan) ? bsumRaw[t] : 0;
    for (int b = t; b < nbkt; b += 256) rk[b] = 0;
    __syncthreads();
    int lane = t & 63, w2 = t >> 6;
    int v = sRaw[t];
    int x = v;
#pragma unroll
    for (int off = 1; off < 64; off <<= 1) {
        int y = __shfl_up(x, off, 64);
        if (lane >= off) x += y;
    }
    if (lane == 63) sWt[w2] = x;
    __syncthreads();
    int base = 0;
#pragma unroll
    for (int q = 0; q < 4; q++) { if (q < w2) base += sWt[q]; }
    sPre[t] = base + x - v;                    // exclusive prefix of chunk sums
    __syncthreads();
    int blk = blockIdx.x;
    for (int b = t; b < nbkt; b += 256) {
        int f = b * nbCount + blk;
        sBase[b] = pre[f] + sPre[f >> 10];     // this block's base in bucket b
    }
    if (blk == 0) {
        for (int b = t; b <= nbkt; b += 256) {
            if (b == nbkt) bucketStart[b] = E;
            else { int f = b * nbCount; bucketStart[b] = pre[f] + sPre[f >> 10]; }
        }
    }
    __syncthreads();
    int e0 = blk * 8192;
    for (int i = t; i < 8192; i += 256) {
        int e = e0 + i;
        if (e < E) {
            int r = ei[e];
            int c = ei[E + e];
            float w = ew[e];
            int b = (unsigned)c >> 7;
            unsigned rank = atomicAdd(&rk[b], 1u);      // LDS atomic
            int2 rec; rec.x = r | ((c & 127) << 17); rec.y = __float_as_int(w);
            recs[sBase[b] + (int)rank] = rec;
        }
    }
}

// Pass D: one block per bucket (128 nodes). Per-node count + weighted degree
// in LDS; dinv = rsqrt(1 + wdeg); ptr; then in-bucket scatter to final CSR
// with csr.y = w * dinv[c] (the *dinv[r] factor is applied by k_norm2).
__global__ __launch_bounds__(256) void k_fin(const int2* __restrict__ recs,
                                             const int* __restrict__ bucketStart,
                                             int2* __restrict__ csr,
                                             int* __restrict__ ptrv,
                                             float* __restrict__ dinv,
                                             int N, int nbkt) {
    __shared__ unsigned scnt[128];
    __shared__ float swdeg[128];
    __shared__ float sdinv[128];
    __shared__ unsigned sTot0;
    int t = threadIdx.x;
    int b = blockIdx.x;
    int e0 = bucketStart[b], e1 = bucketStart[b + 1];
    if (t < 128) { scnt[t] = 0u; swdeg[t] = 0.f; }
    __syncthreads();
    for (int i = e0 + t; i < e1; i += 256) {
        int2 rec = recs[i];
        int cl = (rec.x >> 17) & 127;
        atomicAdd(&scnt[cl], 1u);                       // LDS atomic
        atomicAdd(&swdeg[cl], __int_as_float(rec.y));   // LDS f32 atomic
    }
    __syncthreads();
    unsigned myc = (t < 128) ? scnt[t] : 0u;
    int lane = t & 63, wv = t >> 6;
    unsigned inc = myc;
#pragma unroll
    for (int off = 1; off < 64; off <<= 1) {
        unsigned y = __shfl_up(inc, off, 64);
        if (lane >= off) inc += y;
    }
    if (t == 63) sTot0 = inc;                  // wave-0 total
    __syncthreads();
    unsigned excl = inc - myc + ((wv == 1) ? sTot0 : 0u);
    if (t < 128) {
        scnt[t] = excl;                        // becomes the scatter cursor
        float dv = rsqrtf(1.0f + swdeg[t]);
        sdinv[t] = dv;
        int node = b * 128 + t;
        if (node < N) { ptrv[node] = e0 + (int)excl; dinv[node] = dv; }
    }
    if (b == nbkt - 1 && t == 0) ptrv[N] = e1; // == E
    __syncthreads();
    for (int i = e0 + t; i < e1; i += 256) {
        int2 rec = recs[i];
        int cl = (rec.x >> 17) & 127;
        int r = rec.x & 131071;
        unsigned rank = atomicAdd(&scnt[cl], 1u);       // LDS atomic
        float y = __int_as_float(rec.y) * sdinv[cl];
        int2 mv; mv.x = r; mv.y = __float_as_int(y);
        csr[e0 + (int)rank] = mv;
    }
}

// csr.y *= dinv[r]. Coalesced int2 RMW; dinv gathers are L2/L3-resident.
__global__ __launch_bounds__(256) void k_norm2(int2* __restrict__ csr,
                                               const float* __restrict__ dinv,
                                               int E) {
    int base = blockIdx.x * 1024 + threadIdx.x;
#pragma unroll
    for (int q = 0; q < 4; q++) {
        int e = base + q * 256;
        if (e < E) {
            int2 m = csr[e];
            m.y = __float_as_int(__int_as_float(m.y) * dinv[m.x]);
            csr[e] = m;
        }
    }
}

// One wave per node, paired-edge (R8-proven loop: 4 pairs = 8 edges/iter).
__global__ __launch_bounds__(256) void k_agg(const unsigned* __restrict__ HL,
                                             const int* __restrict__ ptr,
                                             const int2* __restrict__ csr,
                                             const float* __restrict__ dinv,
                                             const float* __restrict__ bias,
                                             unsigned* __restrict__ Hout, int M) {
    __shared__ int2 sM[4 * 64];
    int node = (int)((blockIdx.x * blockDim.x + threadIdx.x) >> 6);
    if (node >= M) return;
    int lane = threadIdx.x & 63;
    int half = lane >> 5;                 // 0: even edges, 1: odd edges
    int q = lane & 31;                    // features 4q .. 4q+3
    int2* mbase = &sM[(threadIdx.x >> 6) * 64];
    int e0 = ptr[node], e1 = ptr[node + 1];
    int deg = e1 - e0;
    int nbv = deg < 64 ? deg : 64;
    if (lane < nbv) mbase[lane] = csr[e0 + lane];   // one coalesced load
    const uint2* HL2 = (const uint2*)HL;            // row = 32 uint2
    float di = dinv[node];
    float sn = (half == 0) ? di * di : 0.f;         // self-loop on half 0 only
    uint2 us = HL2[(size_t)node * 32 + q];
    float a0 = sn * bf_lo(us.x), a1 = sn * bf_hi(us.x);
    float a2 = sn * bf_lo(us.y), a3 = sn * bf_hi(us.y);
    int j = half;
    for (; j + 8 <= nbv; j += 8) {                  // 4 pairs in flight
        int2 m[4]; uint2 u[4];
#pragma unroll
        for (int t = 0; t < 4; t++) m[t] = mbase[j + 2 * t];
#pragma unroll
        for (int t = 0; t < 4; t++) u[t] = HL2[(size_t)m[t].x * 32 + q];
#pragma unroll
        for (int t = 0; t < 4; t++) {
            float nv = __int_as_float(m[t].y);
            a0 += nv * bf_lo(u[t].x); a1 += nv * bf_hi(u[t].x);
            a2 += nv * bf_lo(u[t].y); a3 += nv * bf_hi(u[t].y);
        }
    }
    for (; j < nbv; j += 2) {
        int2 m = mbase[j];
        uint2 u = HL2[(size_t)m.x * 32 + q];
        float nv = __int_as_float(m.y);
        a0 += nv * bf_lo(u.x); a1 += nv * bf_hi(u.x);
        a2 += nv * bf_lo(u.y); a3 += nv * bf_hi(u.y);
    }
    for (int e = e0 + 64 + half; e < e1; e += 2) {  // rare high-degree tail
        int2 m = csr[e];
        uint2 u = HL2[(size_t)m.x * 32 + q];
        float nv = __int_as_float(m.y);
        a0 += nv * bf_lo(u.x); a1 += nv * bf_hi(u.x);
        a2 += nv * bf_lo(u.y); a3 += nv * bf_hi(u.y);
    }
    a0 += __shfl_xor(a0, 32, 64);
    a1 += __shfl_xor(a1, 32, 64);
    a2 += __shfl_xor(a2, 32, 64);
    a3 += __shfl_xor(a3, 32, 64);
    float4 bv = ((const float4*)bias)[q];
    float r0 = fmaxf(a0 + bv.x, 0.f);
    float r1 = fmaxf(a1 + bv.y, 0.f);
    float r2 = fmaxf(a2 + bv.z, 0.f);
    float r3 = fmaxf(a3 + bv.w, 0.f);
    if (half == 0) {
        uint2 pv;
        pv.x = pack_bf16x2(r0, r1);
        pv.y = pack_bf16x2(r2, r3);
        ((uint2*)(Hout + (size_t)node * 64))[q] = pv;
    }
}

// Heterogeneous: blocks[0..nbGemm) = next-layer GEMM reading Hb;
// blocks[nbGemm..nbGemm+G) = pool of the SAME Hb into outp (both depend only
// on the preceding agg). nbGemm=0 -> pool-only (final layer).
__global__ __launch_bounds__(256) void k_gemm_pool(const unsigned* __restrict__ Hb,
                                                   const ushort* __restrict__ WbT,
                                                   unsigned* __restrict__ O, int M,
                                                   const int* __restrict__ gb,
                                                   float* __restrict__ outp,
                                                   int nbGemm) {
    __shared__ unsigned sBuf[8192];            // gemm epilogue / pool partials
    if (blockIdx.x < nbGemm) {
        gemm_tile<false>(Hb, WbT, O, M, blockIdx.x, sBuf);
        return;
    }
    pool_tile(Hb, gb, outp, blockIdx.x - nbGemm, (float*)sBuf);
}

extern "C" void kernel_launch(void* const* d_in, const int* in_sizes, int n_in,
                              void* d_out, int out_size, void* d_ws, size_t ws_size,
                              hipStream_t stream) {
    const float* x     = (const float*)d_in[0];
    const int*   ei    = (const int*)d_in[1];
    const float* ew    = (const float*)d_in[2];
    const int*   batch = (const int*)d_in[3];
    const float* Wt[3] = {(const float*)d_in[4], (const float*)d_in[6], (const float*)d_in[8]};
    const float* bt[3] = {(const float*)d_in[5], (const float*)d_in[7], (const float*)d_in[9]};
    float* out = (float*)d_out;

    const int D = 128;
    const int N = in_sizes[0] / D;       // 100000
    const int E = in_sizes[2];           // 1600000
    const int G = out_size / (3 * D);    // 256

    // workspace carve-up (256 B aligned)
    char* p = (char*)d_ws;
    auto alloc = [&](size_t bytes) {
        void* r = (void*)p;
        p += (bytes + 255) & ~(size_t)255;
        return r;
    };
    int nbkt    = (N + 127) / 128;              // 782 coarse buckets (== nbGemm)
    int nbCount = (E + 8191) / 8192;            // 196 histogram blocks
    int F       = nbkt * nbCount;               // 153272 scan elements
    int nbScan  = (F + 1023) / 1024;            // 150 (<=256 for inline scan)

    int*      ptr    = (int*)alloc((size_t)(N + 1) * 4);
    int*      bsum   = (int*)alloc((size_t)256 * 4);
    int*      gb     = (int*)alloc((size_t)(G + 1) * 4);
    int*      bstart = (int*)alloc((size_t)(nbkt + 1) * 4);
    float*    dinv   = (float*)alloc((size_t)N * 4);
    ushort*   WbT    = (ushort*)alloc((size_t)3 * 16384 * 2);
    int2*     csr    = (int2*)alloc((size_t)E * 8);
    unsigned* bufHL  = (unsigned*)alloc((size_t)N * 64 * 4);  // hl, bf16-packed
    unsigned* bufH   = (unsigned*)alloc((size_t)N * 64 * 4);  // h,  bf16-packed
    // aliases: hist+pre live only before k_fin writes csr; recs (bucketed
    // edge records) dead before k_agg's first write of bufH.
    int*  hist = (int*)csr;                    // F ints (613 KB)
    int*  pre  = hist + F;                     // F ints
    int2* recs = (int2*)bufH;                  // E int2 (12.8 MB)

    int nbGemm = (N + 127) / 128;               // 782 gemm blocks
    int prepWork = 3 * 16384;

    k_prep<<<(prepWork + 255) / 256, 256, 0, stream>>>(batch, gb, G, N,
                                                       Wt[0], Wt[1], Wt[2], WbT);
    // layer-1 GEMM fused with the histogram pass (independent inputs)
    k_phase1<<<nbGemm + nbCount, 256, 0, stream>>>(ei, hist, E, x, WbT,
                                                   bufHL, N, nbGemm, nbCount);
    k_scan1<<<nbScan, 1024, 0, stream>>>(hist, pre, bsum, F);
    k_scat<<<nbCount, 256, 0, stream>>>(ei, ew, pre, bsum, bstart, recs,
                                        E, nbkt, nbCount, nbScan);
    k_fin<<<nbkt, 256, 0, stream>>>(recs, bstart, csr, ptr, dinv, N, nbkt);
    k_norm2<<<(E + 1023) / 1024, 256, 0, stream>>>(csr, dinv, E);

    // L1 aggregate, then fused (gemm_{l+1} + pool_l), final pool-only.
    k_agg<<<(N + 3) / 4, 256, 0, stream>>>(bufHL, ptr, csr, dinv, bt[0], bufH, N);
    k_gemm_pool<<<nbGemm + G, 256, 0, stream>>>(bufH, WbT + 16384, bufHL, N,
                                                gb, out + 0 * (size_t)G * D, nbGemm);
    k_agg<<<(N + 3) / 4, 256, 0, stream>>>(bufHL, ptr, csr, dinv, bt[1], bufH, N);
    k_gemm_pool<<<nbGemm + G, 256, 0, stream>>>(bufH, WbT + 2 * 16384, bufHL, N,
                                                gb, out + 1 * (size_t)G * D, nbGemm);
    k_agg<<<(N + 3) / 4, 256, 0, stream>>>(bufHL, ptr, csr, dinv, bt[2], bufH, N);
    k_gemm_pool<<<G, 256, 0, stream>>>(bufH, WbT, nullptr, 0,
                                       gb, out + 2 * (size_t)G * D, 0);
}

// Round 3
// 524.387 us; speedup vs baseline: 1.1180x; 1.0001x over previous
//
#include <hip/hip_runtime.h>

// ---------------------------------------------------------------------------
// GCN block: 3 x (GCNConv -> ReLU -> global_mean_pool)
// 12 dispatches. ZERO device-scope atomics (R11: 1.6M device atomics are
// rate-limited ~18G/s memory-side regardless of structure). CSR build is a
// 2-level multisplit using only LDS atomics:
//   k_prep:      graph bounds + WbT transpose/cast
//   k_phase1:    heterogeneous: blocks[0..782) = layer-1 MFMA GEMM (fp32 x,
//                in-reg bf16 cast); blocks[782..978) = per-block LDS
//                histogram over 782 coarse buckets (col>>7), plain writes.
//   k_scan1:     1024-chunk exclusive scan over the 153K hist matrix
//   k_scat:      inline LDS scan of chunk sums; LDS-atomic ranks; packed
//                (r|c_local<<17, w) records bucket-contiguous (recs=bufH)
//   k_fin:       one block per bucket: per-node count + weighted degree in
//                LDS, dinv=rsqrt(1+wdeg), ptr, SELF-LOOP EDGE inserted at
//                each node's list head (R12: uniform edge loop in k_agg),
//                in-bucket scatter with csr.y = w*dinv[c]
//   k_norm2:     csr.y *= dinv[r] over E+N edges (self edges -> dinv^2)
//   per layer:   k_agg (uniform paired-edge gather, 16-edge deep-pipelined
//                body — R12: k_agg was latency-bound at 4 loads in flight,
//                VGPR=24, both pipes <50%) ->
//                k_gemm_pool (next-layer GEMM + prev-layer pool fused)
// hist/pre alias csr (dead before k_fin); recs aliases bufH (dead before
// k_agg writes bufH).
// ---------------------------------------------------------------------------

typedef short short8 __attribute__((ext_vector_type(8)));   // 8 bf16 (4 VGPR)
typedef float f32x4  __attribute__((ext_vector_type(4)));   // MFMA C/D

__device__ inline unsigned pack_bf16x2(float a, float b) {
    unsigned ua = __float_as_uint(a);
    ua = (ua + 0x7FFFu + ((ua >> 16) & 1u)) >> 16;       // RNE
    unsigned ub = __float_as_uint(b);
    ub = (ub + 0x7FFFu + ((ub >> 16) & 1u)) >> 16;
    return ua | (ub << 16);
}
__device__ inline ushort bf16_1(float a) {
    unsigned ua = __float_as_uint(a);
    return (ushort)((ua + 0x7FFFu + ((ua >> 16) & 1u)) >> 16);
}
__device__ inline float bf_lo(unsigned u) { return __uint_as_float(u << 16); }
__device__ inline float bf_hi(unsigned u) { return __uint_as_float(u & 0xFFFF0000u); }

// ---- shared device bodies -------------------------------------------------

// One block = 128 rows x 128 cols of hl = H @ W (v_mfma_f32_16x16x32_bf16).
// Wave = 32 rows: 2 m-strips x 8 n-tiles, 64 MFMAs. A-frag 16B/lane
// contiguous (F32IN: 32B fp32 -> in-register bf16 cast). B from WbT[n][k].
// Epilogue via LDS (sOut, 8192 u32) -> coalesced u32 stores.
template <bool F32IN>
__device__ __forceinline__ void gemm_tile(const void* __restrict__ Hin,
                                          const ushort* __restrict__ WbT,
                                          unsigned* __restrict__ O, int M,
                                          int bid, unsigned* sOut) {
    int lane = threadIdx.x & 63;
    int wv = threadIdx.x >> 6;
    int quad = lane >> 4;
    int mrow = lane & 15;
    int m0 = bid * 128 + wv * 32;
    int r0 = m0 + mrow;
    int r1 = r0 + 16;
    int r0c = r0 < M ? r0 : M - 1;             // clamp loads, guard stores
    int r1c = r1 < M ? r1 : M - 1;

    short8 a0[4], a1[4];
    if (F32IN) {
        const float* Hf = (const float*)Hin;
#pragma unroll
        for (int s = 0; s < 4; s++) {          // k-step s covers k in [32s,32s+32)
            const float4* p0 = (const float4*)(Hf + (size_t)r0c * 128 + s * 32 + quad * 8);
            const float4* p1 = (const float4*)(Hf + (size_t)r1c * 128 + s * 32 + quad * 8);
            float4 f0 = p0[0], f1 = p0[1];
            float4 g0 = p1[0], g1 = p1[1];
            union { short8 s8; unsigned u[4]; } t0, t1;
            t0.u[0] = pack_bf16x2(f0.x, f0.y); t0.u[1] = pack_bf16x2(f0.z, f0.w);
            t0.u[2] = pack_bf16x2(f1.x, f1.y); t0.u[3] = pack_bf16x2(f1.z, f1.w);
            t1.u[0] = pack_bf16x2(g0.x, g0.y); t1.u[1] = pack_bf16x2(g0.z, g0.w);
            t1.u[2] = pack_bf16x2(g1.x, g1.y); t1.u[3] = pack_bf16x2(g1.z, g1.w);
            a0[s] = t0.s8; a1[s] = t1.s8;
        }
    } else {
        const unsigned* Hb = (const unsigned*)Hin;
#pragma unroll
        for (int s = 0; s < 4; s++) {
            a0[s] = *(const short8*)(Hb + (size_t)r0c * 64 + s * 16 + quad * 4);
            a1[s] = *(const short8*)(Hb + (size_t)r1c * 64 + s * 16 + quad * 4);
        }
    }
    f32x4 acc0[8], acc1[8];
#pragma unroll
    for (int t = 0; t < 8; t++) {
        acc0[t] = (f32x4){0.f, 0.f, 0.f, 0.f};
        acc1[t] = (f32x4){0.f, 0.f, 0.f, 0.f};
    }
#pragma unroll
    for (int s = 0; s < 4; s++) {
#pragma unroll
        for (int t = 0; t < 8; t++) {
            short8 b = *(const short8*)(WbT + (t * 16 + mrow) * 128 + s * 32 + quad * 8);
            acc0[t] = __builtin_amdgcn_mfma_f32_16x16x32_bf16(a0[s], b, acc0[t], 0, 0, 0);
            acc1[t] = __builtin_amdgcn_mfma_f32_16x16x32_bf16(a1[s], b, acc1[t], 0, 0, 0);
        }
    }
    // C/D layout: col = lane&15, row = quad*4 + reg.
    ushort* so = (ushort*)(sOut + wv * 32 * 64);
#pragma unroll
    for (int t = 0; t < 8; t++) {
#pragma unroll
        for (int r = 0; r < 4; r++) {
            int lr = quad * 4 + r;
            int c = t * 16 + mrow;
            so[lr * 128 + c] = bf16_1(acc0[t][r]);
            so[(lr + 16) * 128 + c] = bf16_1(acc1[t][r]);
        }
    }
    __syncthreads();
    const unsigned* si = sOut + wv * 32 * 64;
#pragma unroll 8
    for (int r = 0; r < 32; r++) {
        int row = m0 + r;
        if (row < M) O[(size_t)row * 64 + lane] = si[r * 64 + lane];
    }
}

// One block per graph: stream the sorted node segment, 4 waves stride it,
// LDS-combine (part = 512 floats), divide by count, write. No atomics.
__device__ __forceinline__ void pool_tile(const unsigned* __restrict__ HB,
                                          const int* __restrict__ gb,
                                          float* __restrict__ outp, int g,
                                          float* part) {
    int lane = threadIdx.x & 63, w = threadIdx.x >> 6;
    int s = gb[g], e = gb[g + 1];
    float ax = 0.f, ay = 0.f;
    for (int i = s + w; i < e; i += 4) {
        unsigned u = HB[(size_t)i * 64 + lane];
        ax += bf_lo(u); ay += bf_hi(u);
    }
    part[w * 128 + lane * 2] = ax;
    part[w * 128 + lane * 2 + 1] = ay;
    __syncthreads();
    if (threadIdx.x < 128) {
        float sum = part[threadIdx.x] + part[128 + threadIdx.x]
                  + part[256 + threadIdx.x] + part[384 + threadIdx.x];
        float c = (float)(e - s);
        outp[g * 128 + threadIdx.x] = sum / fmaxf(c, 1.0f);
    }
}

// ---- kernels --------------------------------------------------------------

// Pre-pass: graph bounds + W transpose+cast.
__global__ void k_prep(const int* __restrict__ batch, int* __restrict__ gb,
                       int G, int N,
                       const float* __restrict__ W0, const float* __restrict__ W1,
                       const float* __restrict__ W2, ushort* __restrict__ WbT) {
    int id = blockIdx.x * blockDim.x + threadIdx.x;
    if (id <= G) {
        int lo = 0, hi = N;
        while (lo < hi) { int mid = (lo + hi) >> 1; if (batch[mid] < id) lo = mid + 1; else hi = mid; }
        gb[id] = lo;
    }
    if (id < 3 * 16384) {
        int l = id >> 14;
        const float* W = (l == 0) ? W0 : ((l == 1) ? W1 : W2);
        int id2 = id & 16383;
        int n = id2 & 127, k = id2 >> 7;
        WbT[l * 16384 + n * 128 + k] = bf16_1(W[k * 128 + n]);
    }
}

// Heterogeneous: blocks[0..nbGemm) = layer-1 GEMM (fp32 x, in-reg bf16 cast);
// blocks[nbGemm..nbGemm+nbCount) = LDS histogram over nbGemm (=nbkt) coarse
// buckets (col>>7), 8192 edges/block, plain hist writes. NO global atomics.
__global__ __launch_bounds__(256) void k_phase1(const int* __restrict__ ei,
                                                int* __restrict__ hist, int E,
                                                const float* __restrict__ x,
                                                const ushort* __restrict__ WbT,
                                                unsigned* __restrict__ O, int M,
                                                int nbGemm, int nbCount) {
    __shared__ unsigned sBuf[8192];            // 32 KB (gemm epilogue / hist)
    if (blockIdx.x < nbGemm) {
        gemm_tile<true>(x, WbT, O, M, blockIdx.x, sBuf);
        return;
    }
    int blk = blockIdx.x - nbGemm;
    unsigned* hcnt = sBuf;                     // nbkt (<=784) counters
    int t = threadIdx.x;
    for (int i = t; i < nbGemm; i += 256) hcnt[i] = 0;
    __syncthreads();
    int base = blk * 8192;
    for (int i = t; i < 8192; i += 256) {
        int e = base + i;
        if (e < E) atomicAdd(&hcnt[(unsigned)ei[E + e] >> 7], 1u);  // LDS atomic
    }
    __syncthreads();
    for (int b = t; b < nbGemm; b += 256)      // bucket-major layout
        hist[b * nbCount + blk] = (int)hcnt[b];
}

// 1024-chunk exclusive scan: pre[i] = chunk-local exclusive prefix,
// bsum[chunk] = chunk total. n = nbkt*nbCount (~153K).
__global__ __launch_bounds__(1024) void k_scan1(const int* __restrict__ cnt,
                                                int* __restrict__ pre,
                                                int* __restrict__ bsum, int n) {
    __shared__ int wsum[16];
    int t = threadIdx.x, lane = t & 63, w = t >> 6;
    int i = blockIdx.x * 1024 + t;
    int v = (i < n) ? cnt[i] : 0;
    int x = v;
#pragma unroll
    for (int off = 1; off < 64; off <<= 1) {
        int y = __shfl_up(x, off, 64);
        if (lane >= off) x += y;
    }
    if (lane == 63) wsum[w] = x;
    __syncthreads();
    int woff = 0, tot = 0;
#pragma unroll
    for (int q = 0; q < 16; q++) { int s = wsum[q]; if (q < w) woff += s; tot += s; }
    if (i < n) pre[i] = woff + x - v;
    if (t == 0) bsum[blockIdx.x] = tot;
}

// Pass C: inline LDS scan of the (<=256) chunk sums; per-bucket bases into
// LDS; per-edge rank via LDS atomic; write packed records into bucket-
// contiguous regions. Block 0 also emits bucketStart[].
__global__ __launch_bounds__(256) void k_scat(const int* __restrict__ ei,
                                              const float* __restrict__ ew,
                                              const int* __restrict__ pre,
                                              const int* __restrict__ bsumRaw,
                                              int* __restrict__ bucketStart,
                                              int2* __restrict__ recs,
                                              int E, int nbkt, int nbCount,
                                              int nbScan) {
    __shared__ int sRaw[256];
    __shared__ int sPre[256];
    __shared__ int sWt[4];
    __shared__ int sBase[784];
    __shared__ unsigned rk[784];
    int t = threadIdx.x;
    sRaw[t] = (t < nbScan) ? bsumRaw[t] : 0;
    for (int b = t; b < nbkt; b += 256) rk[b] = 0;
    __syncthreads();
    int lane = t & 63, w2 = t >> 6;
    int v = sRaw[t];
    int x = v;
#pragma unroll
    for (int off = 1; off < 64; off <<= 1) {
        int y = __shfl_up(x, off, 64);
        if (lane >= off) x += y;
    }
    if (lane == 63) sWt[w2] = x;
    __syncthreads();
    int base = 0;
#pragma unroll
    for (int q = 0; q < 4; q++) { if (q < w2) base += sWt[q]; }
    sPre[t] = base + x - v;                    // exclusive prefix of chunk sums
    __syncthreads();
    int blk = blockIdx.x;
    for (int b = t; b < nbkt; b += 256) {
        int f = b * nbCount + blk;
        sBase[b] = pre[f] + sPre[f >> 10];     // this block's base in bucket b
    }
    if (blk == 0) {
        for (int b = t; b <= nbkt; b += 256) {
            if (b == nbkt) bucketStart[b] = E;
            else { int f = b * nbCount; bucketStart[b] = pre[f] + sPre[f >> 10]; }
        }
    }
    __syncthreads();
    int e0 = blk * 8192;
    for (int i = t; i < 8192; i += 256) {
        int e = e0 + i;
        if (e < E) {
            int r = ei[e];
            int c = ei[E + e];
            float w = ew[e];
            int b = (unsigned)c >> 7;
            unsigned rank = atomicAdd(&rk[b], 1u);      // LDS atomic
            int2 rec; rec.x = r | ((c & 127) << 17); rec.y = __float_as_int(w);
            recs[sBase[b] + (int)rank] = rec;
        }
    }
}

// Pass D: one block per bucket (128 nodes). Per-node count + weighted degree
// in LDS; dinv = rsqrt(1 + wdeg); SELF-LOOP edge written at each node's list
// head (y = dinv[c]; k_norm2's *dinv[r] makes it dinv^2); ptr includes the
// self slot; then in-bucket scatter of real edges with csr.y = w * dinv[c].
// Final layout: node's region = [ptr[node], ptr[node+1]), size cnt+1.
__global__ __launch_bounds__(256) void k_fin(const int2* __restrict__ recs,
                                             const int* __restrict__ bucketStart,
                                             int2* __restrict__ csr,
                                             int* __restrict__ ptrv,
                                             float* __restrict__ dinv,
                                             int N, int nbkt) {
    __shared__ unsigned scnt[128];
    __shared__ float swdeg[128];
    __shared__ float sdinv[128];
    __shared__ unsigned sTot0;
    int t = threadIdx.x;
    int b = blockIdx.x;
    int e0 = bucketStart[b], e1 = bucketStart[b + 1];
    int FB = e0 + b * 128;                     // final base incl. prior selfs
    if (t < 128) { scnt[t] = 0u; swdeg[t] = 0.f; }
    __syncthreads();
    for (int i = e0 + t; i < e1; i += 256) {
        int2 rec = recs[i];
        int cl = (rec.x >> 17) & 127;
        atomicAdd(&scnt[cl], 1u);                       // LDS atomic
        atomicAdd(&swdeg[cl], __int_as_float(rec.y));   // LDS f32 atomic
    }
    __syncthreads();
    unsigned myc = (t < 128) ? scnt[t] : 0u;
    int lane = t & 63, wv = t >> 6;
    unsigned inc = myc;
#pragma unroll
    for (int off = 1; off < 64; off <<= 1) {
        unsigned y = __shfl_up(inc, off, 64);
        if (lane >= off) inc += y;
    }
    if (t == 63) sTot0 = inc;                  // wave-0 total
    __syncthreads();
    unsigned excl = inc - myc + ((wv == 1) ? sTot0 : 0u);
    if (t < 128) {
        float dv = rsqrtf(1.0f + swdeg[t]);
        sdinv[t] = dv;
        scnt[t] = excl + (unsigned)t + 1u;     // scatter cursor (rel. to FB)
        int node = b * 128 + t;
        int start = FB + (int)excl + t;
        if (node < N) {
            ptrv[node] = start;
            dinv[node] = dv;
            int2 sv; sv.x = node; sv.y = __float_as_int(dv);  // self: w=1*dinv[c]
            csr[start] = sv;
        }
    }
    if (b == nbkt - 1 && t == 0) ptrv[N] = e1 + N;  // = E + N
    __syncthreads();
    for (int i = e0 + t; i < e1; i += 256) {
        int2 rec = recs[i];
        int cl = (rec.x >> 17) & 127;
        int r = rec.x & 131071;
        unsigned rank = atomicAdd(&scnt[cl], 1u);       // LDS atomic
        float y = __int_as_float(rec.y) * sdinv[cl];
        int2 mv; mv.x = r; mv.y = __float_as_int(y);
        csr[FB + (int)rank] = mv;
    }
}

// csr.y *= dinv[r] over E+N entries (self edges become dinv^2). Coalesced
// int2 RMW; dinv gathers L2/L3-resident.
__global__ __launch_bounds__(256) void k_norm2(int2* __restrict__ csr,
                                               const float* __restrict__ dinv,
                                               int E) {
    int base = blockIdx.x * 1024 + threadIdx.x;
#pragma unroll
    for (int q = 0; q < 4; q++) {
        int e = base + q * 256;
        if (e < E) {
            int2 m = csr[e];
            m.y = __float_as_int(__int_as_float(m.y) * dinv[m.x]);
            csr[e] = m;
        }
    }
}

// One wave per node, uniform edge list (self-loop is edge 0). Deep-pipelined:
// 8-pair (16-edge) body keeps 8 gathers in flight per half-wave (R12: the
// 4-pair body was latency-bound — VGPR=24, VALUBusy 48%, HBM 42%).
__global__ __launch_bounds__(256) void k_agg(const unsigned* __restrict__ HL,
                                             const int* __restrict__ ptr,
                                             const int2* __restrict__ csr,
                                             const float* __restrict__ bias,
                                             unsigned* __restrict__ Hout, int M) {
    __shared__ int2 sM[4 * 64];
    int node = (int)((blockIdx.x * blockDim.x + threadIdx.x) >> 6);
    if (node >= M) return;
    int lane = threadIdx.x & 63;
    int half = lane >> 5;                 // 0: even edges, 1: odd edges
    int q = lane & 31;                    // features 4q .. 4q+3
    int2* mbase = &sM[(threadIdx.x >> 6) * 64];
    int e0 = ptr[node], e1 = ptr[node + 1];
    int deg = e1 - e0;                    // includes self edge
    int nbv = deg < 64 ? deg : 64;
    if (lane < nbv) mbase[lane] = csr[e0 + lane];   // one coalesced load
    const uint2* HL2 = (const uint2*)HL;            // row = 32 uint2
    float a0 = 0.f, a1 = 0.f, a2 = 0.f, a3 = 0.f;
    int j = half;
    for (; j + 16 <= nbv; j += 16) {                // 8 pairs in flight
        int2 m[8]; uint2 u[8];
#pragma unroll
        for (int t = 0; t < 8; t++) m[t] = mbase[j + 2 * t];
#pragma unroll
        for (int t = 0; t < 8; t++) u[t] = HL2[(size_t)m[t].x * 32 + q];
#pragma unroll
        for (int t = 0; t < 8; t++) {
            float nv = __int_as_float(m[t].y);
            a0 += nv * bf_lo(u[t].x); a1 += nv * bf_hi(u[t].x);
            a2 += nv * bf_lo(u[t].y); a3 += nv * bf_hi(u[t].y);
        }
    }
    for (; j + 8 <= nbv; j += 8) {                  // 4 pairs in flight
        int2 m[4]; uint2 u[4];
#pragma unroll
        for (int t = 0; t < 4; t++) m[t] = mbase[j + 2 * t];
#pragma unroll
        for (int t = 0; t < 4; t++) u[t] = HL2[(size_t)m[t].x * 32 + q];
#pragma unroll
        for (int t = 0; t < 4; t++) {
            float nv = __int_as_float(m[t].y);
            a0 += nv * bf_lo(u[t].x); a1 += nv * bf_hi(u[t].x);
            a2 += nv * bf_lo(u[t].y); a3 += nv * bf_hi(u[t].y);
        }
    }
    for (; j < nbv; j += 2) {
        int2 m = mbase[j];
        uint2 u = HL2[(size_t)m.x * 32 + q];
        float nv = __int_as_float(m.y);
        a0 += nv * bf_lo(u.x); a1 += nv * bf_hi(u.x);
        a2 += nv * bf_lo(u.y); a3 += nv * bf_hi(u.y);
    }
    for (int e = e0 + 64 + half; e < e1; e += 2) {  // rare high-degree tail
        int2 m = csr[e];
        uint2 u = HL2[(size_t)m.x * 32 + q];
        float nv = __int_as_float(m.y);
        a0 += nv * bf_lo(u.x); a1 += nv * bf_hi(u.x);
        a2 += nv * bf_lo(u.y); a3 += nv * bf_hi(u.y);
    }
    a0 += __shfl_xor(a0, 32, 64);
    a1 += __shfl_xor(a1, 32, 64);
    a2 += __shfl_xor(a2, 32, 64);
    a3 += __shfl_xor(a3, 32, 64);
    float4 bv = ((const float4*)bias)[q];
    float r0 = fmaxf(a0 + bv.x, 0.f);
    float r1 = fmaxf(a1 + bv.y, 0.f);
    float r2 = fmaxf(a2 + bv.z, 0.f);
    float r3 = fmaxf(a3 + bv.w, 0.f);
    if (half == 0) {
        uint2 pv;
        pv.x = pack_bf16x2(r0, r1);
        pv.y = pack_bf16x2(r2, r3);
        ((uint2*)(Hout + (size_t)node * 64))[q] = pv;
    }
}

// Heterogeneous: blocks[0..nbGemm) = next-layer GEMM reading Hb;
// blocks[nbGemm..nbGemm+G) = pool of the SAME Hb into outp (both depend only
// on the preceding agg). nbGemm=0 -> pool-only (final layer).
__global__ __launch_bounds__(256) void k_gemm_pool(const unsigned* __restrict__ Hb,
                                                   const ushort* __restrict__ WbT,
                                                   unsigned* __restrict__ O, int M,
                                                   const int* __restrict__ gb,
                                                   float* __restrict__ outp,
                                                   int nbGemm) {
    __shared__ unsigned sBuf[8192];            // gemm epilogue / pool partials
    if (blockIdx.x < nbGemm) {
        gemm_tile<false>(Hb, WbT, O, M, blockIdx.x, sBuf);
        return;
    }
    pool_tile(Hb, gb, outp, blockIdx.x - nbGemm, (float*)sBuf);
}

extern "C" void kernel_launch(void* const* d_in, const int* in_sizes, int n_in,
                              void* d_out, int out_size, void* d_ws, size_t ws_size,
                              hipStream_t stream) {
    const float* x     = (const float*)d_in[0];
    const int*   ei    = (const int*)d_in[1];
    const float* ew    = (const float*)d_in[2];
    const int*   batch = (const int*)d_in[3];
    const float* Wt[3] = {(const float*)d_in[4], (const float*)d_in[6], (const float*)d_in[8]};
    const float* bt[3] = {(const float*)d_in[5], (const float*)d_in[7], (const float*)d_in[9]};
    float* out = (float*)d_out;

    const int D = 128;
    const int N = in_sizes[0] / D;       // 100000
    const int E = in_sizes[2];           // 1600000
    const int G = out_size / (3 * D);    // 256

    // workspace carve-up (256 B aligned)
    char* p = (char*)d_ws;
    auto alloc = [&](size_t bytes) {
        void* r = (void*)p;
        p += (bytes + 255) & ~(size_t)255;
        return r;
    };
    int nbkt    = (N + 127) / 128;              // 782 coarse buckets (== nbGemm)
    int nbCount = (E + 8191) / 8192;            // 196 histogram blocks
    int F       = nbkt * nbCount;               // 153272 scan elements
    int nbScan  = (F + 1023) / 1024;            // 150 (<=256 for inline scan)

    int*      ptr    = (int*)alloc((size_t)(N + 1) * 4);
    int*      bsum   = (int*)alloc((size_t)256 * 4);
    int*      gb     = (int*)alloc((size_t)(G + 1) * 4);
    int*      bstart = (int*)alloc((size_t)(nbkt + 1) * 4);
    float*    dinv   = (float*)alloc((size_t)N * 4);
    ushort*   WbT    = (ushort*)alloc((size_t)3 * 16384 * 2);
    int2*     csr    = (int2*)alloc((size_t)(E + N) * 8);     // incl. selfs
    unsigned* bufHL  = (unsigned*)alloc((size_t)N * 64 * 4);  // hl, bf16-packed
    unsigned* bufH   = (unsigned*)alloc((size_t)N * 64 * 4);  // h,  bf16-packed
    // aliases: hist+pre live only before k_fin writes csr; recs (bucketed
    // edge records) dead before k_agg's first write of bufH.
    int*  hist = (int*)csr;                    // F ints (613 KB)
    int*  pre  = hist + F;                     // F ints
    int2* recs = (int2*)bufH;                  // E int2 (12.8 MB)

    int nbGemm = (N + 127) / 128;               // 782 gemm blocks
    int prepWork = 3 * 16384;

    k_prep<<<(prepWork + 255) / 256, 256, 0, stream>>>(batch, gb, G, N,
                                                       Wt[0], Wt[1], Wt[2], WbT);
    // layer-1 GEMM fused with the histogram pass (independent inputs)
    k_phase1<<<nbGemm + nbCount, 256, 0, stream>>>(ei, hist, E, x, WbT,
                                                   bufHL, N, nbGemm, nbCount);
    k_scan1<<<nbScan, 1024, 0, stream>>>(hist, pre, bsum, F);
    k_scat<<<nbCount, 256, 0, stream>>>(ei, ew, pre, bsum, bstart, recs,
                                        E, nbkt, nbCount, nbScan);
    k_fin<<<nbkt, 256, 0, stream>>>(recs, bstart, csr, ptr, dinv, N, nbkt);
    k_norm2<<<(E + N + 1023) / 1024, 256, 0, stream>>>(csr, dinv, E + N);

    // L1 aggregate, then fused (gemm_{l+1} + pool_l), final pool-only.
    k_agg<<<(N + 3) / 4, 256, 0, stream>>>(bufHL, ptr, csr, bt[0], bufH, N);
    k_gemm_pool<<<nbGemm + G, 256, 0, stream>>>(bufH, WbT + 16384, bufHL, N,
                                                gb, out + 0 * (size_t)G * D, nbGemm);
    k_agg<<<(N + 3) / 4, 256, 0, stream>>>(bufHL, ptr, csr, bt[1], bufH, N);
    k_gemm_pool<<<nbGemm + G, 256, 0, stream>>>(bufH, WbT + 2 * 16384, bufHL, N,
                                                gb, out + 1 * (size_t)G * D, nbGemm);
    k_agg<<<(N + 3) / 4, 256, 0, stream>>>(bufHL, ptr, csr, bt[2], bufH, N);
    k_gemm_pool<<<G, 256, 0, stream>>>(bufH, WbT, nullptr, 0,
                                       gb, out + 2 * (size_t)G * D, 0);
}